// Round 2
// baseline (329.112 us; speedup 1.0000x reference)
//
#include <hip/hip_runtime.h>

#define NUM_ENT 200000
#define BQ 128
#define DIM 128
#define TB 32   // queries per block (BQ/TB = gridDim.y = 4)

// Kernel 1: query[b][d] = E[h[b]][d] + R[r[b]][d] + T[t[b]][d]
__global__ void build_query_kernel(const float* __restrict__ ent,
                                   const float* __restrict__ rel,
                                   const float* __restrict__ tim,
                                   const int* __restrict__ h_idx,
                                   const int* __restrict__ r_idx,
                                   const int* __restrict__ t_idx,
                                   float* __restrict__ q) {
    const int b = blockIdx.x;
    const int d = threadIdx.x;
    q[b * DIM + d] = ent[(size_t)h_idx[b] * DIM + d]
                   + rel[(size_t)r_idx[b] * DIM + d]
                   + tim[(size_t)t_idx[b] * DIM + d];
}

// Kernel 2: one entity per thread (lane-coalesced in n); one 32-query tile
// per block (blockIdx.y). q loads are wave-uniform -> scalarized by compiler.
__global__ __launch_bounds__(256) void score_kernel(
        const float* __restrict__ ent,
        const float* __restrict__ q,
        float* __restrict__ out) {
    const int n = blockIdx.x * 256 + threadIdx.x;
    const bool valid = (n < NUM_ENT);
    const int nc = valid ? n : (NUM_ENT - 1);
    const float* __restrict__ erow = ent + (size_t)nc * DIM;
    const int bt = blockIdx.y * TB;

    float acc[TB];
#pragma unroll
    for (int i = 0; i < TB; ++i) acc[i] = 0.0f;

#pragma unroll 2
    for (int dc = 0; dc < DIM; dc += 8) {
        float4 e0 = *(const float4*)(erow + dc);
        float4 e1 = *(const float4*)(erow + dc + 4);
#pragma unroll
        for (int tb = 0; tb < TB; ++tb) {
            const float* qp = q + (bt + tb) * DIM + dc;
            float4 q0 = *(const float4*)(qp);
            float4 q1 = *(const float4*)(qp + 4);
            float d0 = fabsf(q0.x - e0.x);
            float d1 = fabsf(q0.y - e0.y);
            float d2 = fabsf(q0.z - e0.z);
            float d3 = fabsf(q0.w - e0.w);
            float d4 = fabsf(q1.x - e1.x);
            float d5 = fabsf(q1.y - e1.y);
            float d6 = fabsf(q1.z - e1.z);
            float d7 = fabsf(q1.w - e1.w);
            // tree sum: adds consume abs via VOP3 input modifiers, ILP 8
            acc[tb] += ((d0 + d1) + (d2 + d3)) + ((d4 + d5) + (d6 + d7));
        }
    }
    if (valid) {
#pragma unroll
        for (int tb = 0; tb < TB; ++tb)
            out[(size_t)(bt + tb) * NUM_ENT + n] = -acc[tb];
    }
}

extern "C" void kernel_launch(void* const* d_in, const int* in_sizes, int n_in,
                              void* d_out, int out_size, void* d_ws, size_t ws_size,
                              hipStream_t stream) {
    const float* ent = (const float*)d_in[0];
    const float* rel = (const float*)d_in[1];
    const float* tim = (const float*)d_in[2];
    const int*   h_idx = (const int*)d_in[3];
    const int*   r_idx = (const int*)d_in[4];
    const int*   t_idx = (const int*)d_in[5];
    float* out = (float*)d_out;
    float* q   = (float*)d_ws;   // 128*128 f32 = 64 KB scratch

    build_query_kernel<<<BQ, DIM, 0, stream>>>(ent, rel, tim, h_idx, r_idx, t_idx, q);

    const int nblocks = (NUM_ENT + 255) / 256;
    dim3 grid(nblocks, BQ / TB);
    score_kernel<<<grid, 256, 0, stream>>>(ent, q, out);
}

// Round 3
// 304.955 us; speedup vs baseline: 1.0792x; 1.0792x over previous
//
#include <hip/hip_runtime.h>

#define NUM_ENT 200000
#define BQ 128
#define DIM 128
#define NE 4     // entities per thread
#define TBQ 16   // queries per block (BQ/TBQ = gridDim.y = 8)

// Kernel 1: query[b][d] = E[h[b]][d] + R[r[b]][d] + T[t[b]][d]
__global__ void build_query_kernel(const float* __restrict__ ent,
                                   const float* __restrict__ rel,
                                   const float* __restrict__ tim,
                                   const int* __restrict__ h_idx,
                                   const int* __restrict__ r_idx,
                                   const int* __restrict__ t_idx,
                                   float* __restrict__ q) {
    const int b = blockIdx.x;
    const int d = threadIdx.x;
    q[b * DIM + d] = ent[(size_t)h_idx[b] * DIM + d]
                   + rel[(size_t)r_idx[b] * DIM + d]
                   + tim[(size_t)t_idx[b] * DIM + d];
}

// Kernel 2: each thread scores NE=4 entities (rows n0 + k*256, coalesced per k)
// against TBQ=16 queries. q loads (wave-uniform) amortize over 4 entities;
// e-chunk loads amortize over 16 queries: 1024 VALU ops per 40 loads.
__global__ __launch_bounds__(256) void score_kernel(
        const float* __restrict__ ent,
        const float* __restrict__ q,
        float* __restrict__ out) {
    const int tid = threadIdx.x;
    const int n0 = blockIdx.x * (256 * NE) + tid;   // rows n0 + ne*256
    const int qt = blockIdx.y * TBQ;

    float acc[NE][TBQ];
#pragma unroll
    for (int ne = 0; ne < NE; ++ne)
#pragma unroll
        for (int tb = 0; tb < TBQ; ++tb) acc[ne][tb] = 0.0f;

    const float* __restrict__ qbase = q + qt * DIM;

#pragma unroll 2
    for (int dc = 0; dc < DIM; dc += 8) {
        float4 e0[NE], e1[NE];
#pragma unroll
        for (int ne = 0; ne < NE; ++ne) {
            int n = n0 + ne * 256;
            int nc = (n < NUM_ENT) ? n : (NUM_ENT - 1);
            const float* ep = ent + (size_t)nc * DIM + dc;
            e0[ne] = *(const float4*)(ep);
            e1[ne] = *(const float4*)(ep + 4);
        }
#pragma unroll
        for (int tb = 0; tb < TBQ; ++tb) {
            const float* qp = qbase + tb * DIM + dc;
            float4 q0 = *(const float4*)(qp);
            float4 q1 = *(const float4*)(qp + 4);
#pragma unroll
            for (int ne = 0; ne < NE; ++ne) {
                float d0 = fabsf(q0.x - e0[ne].x);
                float d1 = fabsf(q0.y - e0[ne].y);
                float d2 = fabsf(q0.z - e0[ne].z);
                float d3 = fabsf(q0.w - e0[ne].w);
                float d4 = fabsf(q1.x - e1[ne].x);
                float d5 = fabsf(q1.y - e1[ne].y);
                float d6 = fabsf(q1.z - e1[ne].z);
                float d7 = fabsf(q1.w - e1[ne].w);
                acc[ne][tb] += ((d0 + d1) + (d2 + d3)) + ((d4 + d5) + (d6 + d7));
            }
        }
    }

#pragma unroll
    for (int ne = 0; ne < NE; ++ne) {
        int n = n0 + ne * 256;
        if (n < NUM_ENT) {
#pragma unroll
            for (int tb = 0; tb < TBQ; ++tb)
                out[(size_t)(qt + tb) * NUM_ENT + n] = -acc[ne][tb];
        }
    }
}

extern "C" void kernel_launch(void* const* d_in, const int* in_sizes, int n_in,
                              void* d_out, int out_size, void* d_ws, size_t ws_size,
                              hipStream_t stream) {
    const float* ent = (const float*)d_in[0];
    const float* rel = (const float*)d_in[1];
    const float* tim = (const float*)d_in[2];
    const int*   h_idx = (const int*)d_in[3];
    const int*   r_idx = (const int*)d_in[4];
    const int*   t_idx = (const int*)d_in[5];
    float* out = (float*)d_out;
    float* q   = (float*)d_ws;   // 128*128 f32 = 64 KB scratch

    build_query_kernel<<<BQ, DIM, 0, stream>>>(ent, rel, tim, h_idx, r_idx, t_idx, q);

    const int nblocks = (NUM_ENT + 256 * NE - 1) / (256 * NE);   // 196
    dim3 grid(nblocks, BQ / TBQ);                                 // (196, 8)
    score_kernel<<<grid, 256, 0, stream>>>(ent, q, out);
}